// Round 4
// baseline (312.599 us; speedup 1.0000x reference)
//
#include <hip/hip_runtime.h>
#include <math.h>

#define BB 8
#define SS 4096
#define HH 1024
#define ROWS (BB * HH)   // 8192
#define KTOP 8
#define NS 32            // s-chunks; pairs ws = ROWS*NS*8*8B = 16.8 MB
#define SC (SS / NS)     // 128 s per chunk
#define SCW (SC / 4)     // 32 s per wave-subchunk

// Branch-free insert of XD into descending sorted D[0..7] (top-8 of 9):
//   D[i] <- max(D[i], min(D[i-1], XD))
// 15 v_{min,max}_f64, dependency depth 2, no branches, no masks.
// Scores embedded exactly in the double's high bits (f32->f64 exact); the
// value's f32 bits >> 2 live in the 29 free low mantissa bits, so payload
// never reorders two distinct f32 scores. t==0 -> score -inf, payload 0.
#define INSERTD(D, XD) do {                                               \
    const double _x = (XD);                                               \
    const double _n0 = fmax(D[0], _x);                                    \
    const double _n1 = fmax(D[1], fmin(D[0], _x));                        \
    const double _n2 = fmax(D[2], fmin(D[1], _x));                        \
    const double _n3 = fmax(D[3], fmin(D[2], _x));                        \
    const double _n4 = fmax(D[4], fmin(D[3], _x));                        \
    const double _n5 = fmax(D[5], fmin(D[4], _x));                        \
    const double _n6 = fmax(D[6], fmin(D[5], _x));                        \
    const double _n7 = fmax(D[7], fmin(D[6], _x));                        \
    D[0] = _n0; D[1] = _n1; D[2] = _n2; D[3] = _n3;                       \
    D[4] = _n4; D[5] = _n5; D[6] = _n6; D[7] = _n7;                       \
  } while (0)

#define AS1 __attribute__((address_space(1)))
#define AS3 __attribute__((address_space(3)))
// Async global->LDS DMA, 16B per lane. Side-effecting intrinsic: the
// compiler cannot sink it (R1/R2 showed register-staged loads always get
// sunk, VGPR=40, MLP~4). Zero destination VGPRs -> all 16 staging instrs
// of a wave are truly in flight. LDS dest = wave-uniform base + lane*16.
static __device__ __forceinline__ void stage16(const float* g, float* l) {
  __builtin_amdgcn_global_load_lds((AS1 const void*)g, (AS3 void*)l, 16, 0, 0);
}

// Kernel 1: per-(row, s-chunk) top-8 of log(relu(h)) + gumbel.
// Block = 64 rows x 4 wave-subchunks, grid (NS, ROWS/64) = 4096 blocks.
// Each wave DMA-stages its own 8KB hidden + 8KB gumbel slice to LDS
// (16 x global_load_lds), then consumes quarter-by-quarter with counted
// s_waitcnt vmcnt(12/8/4/0) — no cross-wave barrier until the merge tree.
// LDS layouts follow the DMA's linear lane*16 order:
//   h_lds[w][s 0..31][h 0..63]   (reads: consecutive dwords, conflict-free)
//   g_lds[w][i 0..7][row 0..63][4] (reads: stride-16B b128, conflict-free)
// The 64KB staging LDS is reused (post-barrier) for the 18KB merge tree.
__global__ __launch_bounds__(256) void topk_partial(
    const float* __restrict__ hidden, const float* __restrict__ gumbel,
    double* __restrict__ pairs) {
  __shared__ __align__(16) char smem[65536];
  float* const h_lds = (float*)smem;            // [4][32][64]
  float* const g_lds = (float*)(smem + 32768);  // [4][8][64][4]
  double* const lst  = (double*)smem;           // reused: [256][9] = 18KB

  const int tid = threadIdx.x;
  const int rl  = tid & 63;         // local row (lane)
  const int w   = tid >> 6;         // wave = s-subchunk
  const int sc  = blockIdx.x;
  const int rb  = blockIdx.y;       // 64-row block
  const int r   = rb * 64 + rl;
  const int b   = rb >> 4;          // 64-row blocks never straddle a b
  const int h0  = (rb & 15) << 6;
  const int s_w0 = sc * SC + w * SCW;

  // per-lane global sources
  const float* gsrc = gumbel + (size_t)r * SS + s_w0;  // own row, 16B per instr
  const float* hsrc = hidden + ((size_t)b * SS + s_w0) * HH + h0 + ((rl & 15) << 2);
  const int hs_lane = rl >> 4;      // lane's s-offset within a 4-s-row instr

  // wave-uniform LDS dests
  float* const gdst = g_lds + w * (8 * 64 * 4);
  float* const hdst = h_lds + w * (32 * 64);

  // issue all 16 staging instrs, quarter order: [g,g,h,h] x4
#pragma unroll
  for (int q = 0; q < 4; ++q) {
#pragma unroll
    for (int ii = 0; ii < 2; ++ii) {
      const int i = q * 2 + ii;
      stage16(gsrc + i * 4, gdst + i * 256);
    }
#pragma unroll
    for (int ii = 0; ii < 2; ++ii) {
      const int i = q * 2 + ii;
      stage16(hsrc + (size_t)(i * 4 + hs_lane) * HH, hdst + i * 256);
    }
  }

  double D[8];
#pragma unroll
  for (int i = 0; i < KTOP; ++i) D[i] = -(double)INFINITY;

  const float* const grd = gdst + (rl << 2);  // &g[w][0][rl][0], +256 per i
  const float* const hrd = hdst + rl;         // &h[w][0][rl],   +64 per s

#pragma unroll
  for (int q = 0; q < 4; ++q) {
    // wait for this quarter's 4 loads (FIFO: 16 issued, 4*(q+1) needed)
    if (q == 0)      asm volatile("s_waitcnt vmcnt(12)" ::: "memory");
    else if (q == 1) asm volatile("s_waitcnt vmcnt(8)"  ::: "memory");
    else if (q == 2) asm volatile("s_waitcnt vmcnt(4)"  ::: "memory");
    else             asm volatile("s_waitcnt vmcnt(0)"  ::: "memory");
    __builtin_amdgcn_sched_barrier(0);   // rule #18: pin reads below the wait
#pragma unroll
    for (int ii = 0; ii < 2; ++ii) {
      const int i = q * 2 + ii;
      const float4 gg = *(const float4*)(grd + i * 256);
#pragma unroll
      for (int c = 0; c < 4; ++c) {
        const float t   = fmaxf(hrd[(i * 4 + c) * 64], 0.0f);
        const float scv = logf(t) + ((const float*)&gg)[c];
        double xd = (double)scv;             // exact; low 29 mantissa bits 0
        xd = __longlong_as_double(__double_as_longlong(xd)
               | (long long)(__float_as_uint(t) >> 2));
        INSERTD(D, xd);
      }
    }
  }

  __syncthreads();   // all waves done with staged LDS; safe to reuse as lst
  // publish per-subchunk top-8
#pragma unroll
  for (int j = 0; j < KTOP; ++j) lst[(w * 64 + rl) * 9 + j] = D[j];
  __syncthreads();
  // stage 1: wave 0 merges list1, wave 2 merges list3
  if (w == 0 || w == 2) {
#pragma unroll
    for (int j = 0; j < KTOP; ++j) {
      const double xd = lst[((w + 1) * 64 + rl) * 9 + j];
      INSERTD(D, xd);
    }
    if (w == 2) {
#pragma unroll
      for (int j = 0; j < KTOP; ++j) lst[(2 * 64 + rl) * 9 + j] = D[j];
    }
  }
  __syncthreads();
  // stage 2: wave 0 merges merged23, writes row's chunk top-8 (64B contig)
  if (w == 0) {
#pragma unroll
    for (int j = 0; j < KTOP; ++j) {
      const double xd = lst[(2 * 64 + rl) * 9 + j];
      INSERTD(D, xd);
    }
    double* __restrict__ op = pairs + ((size_t)r * NS + sc) * KTOP;
#pragma unroll
    for (int j = 0; j < KTOP; ++j) op[j] = D[j];
  }
}

// Kernel 2: merge NS chunk top-8s per row -> pooled[r] = sum of top-8 values.
// 16 threads/row (was 8): half the serial INSERT chain per thread, 2x blocks
// (512) for occupancy. 4-level LDS tree. block 256 -> 16 rows/block.
__global__ __launch_bounds__(256) void topk_merge(
    const double* __restrict__ pairs, float* __restrict__ pooled) {
  __shared__ double ls[256 * 9];    // [slot=tid][j], padded
  const int tid  = threadIdx.x;
  const int rloc = tid >> 4;        // 0..15
  const int q    = tid & 15;        // chunk group
  const int r    = blockIdx.x * 16 + rloc;
  const int slot = tid;

  double D[8];
#pragma unroll
  for (int i = 0; i < KTOP; ++i) D[i] = -(double)INFINITY;

  const int cpg = NS / 16;          // 2 chunks per group
  const double2* __restrict__ p =
      (const double2*)(pairs + ((size_t)r * NS + q * cpg) * KTOP);
#pragma unroll
  for (int i = 0; i < cpg * KTOP / 2; ++i) {
    const double2 two = p[i];
    INSERTD(D, two.x);
    INSERTD(D, two.y);
  }
#pragma unroll
  for (int j = 0; j < KTOP; ++j) ls[slot * 9 + j] = D[j];
  __syncthreads();
  if ((q & 1) == 0) {               // level 1
#pragma unroll
    for (int j = 0; j < KTOP; ++j) INSERTD(D, ls[(slot + 1) * 9 + j]);
#pragma unroll
    for (int j = 0; j < KTOP; ++j) ls[slot * 9 + j] = D[j];
  }
  __syncthreads();
  if ((q & 3) == 0) {               // level 2
#pragma unroll
    for (int j = 0; j < KTOP; ++j) INSERTD(D, ls[(slot + 2) * 9 + j]);
#pragma unroll
    for (int j = 0; j < KTOP; ++j) ls[slot * 9 + j] = D[j];
  }
  __syncthreads();
  if ((q & 7) == 0) {               // level 3
#pragma unroll
    for (int j = 0; j < KTOP; ++j) INSERTD(D, ls[(slot + 4) * 9 + j]);
#pragma unroll
    for (int j = 0; j < KTOP; ++j) ls[slot * 9 + j] = D[j];
  }
  __syncthreads();
  if (q == 0) {                     // level 4: decode payloads, sum
#pragma unroll
    for (int j = 0; j < KTOP; ++j) INSERTD(D, ls[(slot + 8) * 9 + j]);
    float sum = 0.0f;
#pragma unroll
    for (int j = 0; j < KTOP; ++j) {
      const unsigned int lo = (unsigned int)__double_as_longlong(D[j]);
      sum += __uint_as_float((lo & 0x1FFFFFFFu) << 2);
    }
    // all-zero rows: every slot stayed -inf -> payload 0 -> sum 0 (matches ref)
    pooled[r] = sum;
  }
}

// Kernel 3: out[b][j] = tanh(sum_h pooled[b][h] * W[j][h] + bias[j]).
__global__ __launch_bounds__(256) void linear_tanh(
    const float* __restrict__ pooled, const float* __restrict__ W,
    const float* __restrict__ bias, float* __restrict__ out) {
  __shared__ float lp[ROWS];  // 32 KB: full pooled
  const int tid = threadIdx.x;
#pragma unroll
  for (int i = 0; i < ROWS / 4 / 256; ++i)
    ((float4*)lp)[i * 256 + tid] = ((const float4*)pooled)[i * 256 + tid];
  __syncthreads();

  const int wave = tid >> 6;
  const int lane = tid & 63;
  const int j = blockIdx.x * 4 + wave;

  float acc[BB];
#pragma unroll
  for (int bb = 0; bb < BB; ++bb) acc[bb] = 0.0f;
#pragma unroll
  for (int k0 = 0; k0 < HH; k0 += 256) {
    const float4 w4 = *(const float4*)&W[(size_t)j * HH + k0 + lane * 4];
#pragma unroll
    for (int bb = 0; bb < BB; ++bb) {
      const float4 p4 = *(const float4*)&lp[bb * HH + k0 + lane * 4];
      acc[bb] += w4.x * p4.x + w4.y * p4.y + w4.z * p4.z + w4.w * p4.w;
    }
  }
#pragma unroll
  for (int bb = 0; bb < BB; ++bb) {
    float a = acc[bb];
    for (int off = 32; off > 0; off >>= 1) a += __shfl_down(a, off, 64);
    if (lane == 0) out[(size_t)bb * HH + j] = tanhf(a + bias[j]);
  }
}

extern "C" void kernel_launch(void* const* d_in, const int* in_sizes, int n_in,
                              void* d_out, int out_size, void* d_ws, size_t ws_size,
                              hipStream_t stream) {
  const float* hidden = (const float*)d_in[0];
  const float* gumbel = (const float*)d_in[1];
  const float* W      = (const float*)d_in[2];
  const float* bias   = (const float*)d_in[3];
  float* out          = (float*)d_out;

  double* pairs  = (double*)d_ws;
  float*  pooled = (float*)((char*)d_ws
                   + (size_t)ROWS * NS * KTOP * sizeof(double));

  topk_partial<<<dim3(NS, ROWS / 64), dim3(256), 0, stream>>>(hidden, gumbel, pairs);
  topk_merge<<<dim3(ROWS / 16), dim3(256), 0, stream>>>(pairs, pooled);
  linear_tanh<<<dim3(HH / 4), dim3(256), 0, stream>>>(pooled, W, bias, out);
}